// Round 1
// baseline (288.404 us; speedup 1.0000x reference)
//
#include <hip/hip_runtime.h>
#include <hip/hip_bf16.h>
#include <stdint.h>

#define M_POS 0.5f
#define M_NEG 0.1f
#define LAM_NEG 1.0f

typedef __attribute__((ext_vector_type(4))) float floatx4;  // 16x16 MFMA accumulator
typedef __attribute__((ext_vector_type(8))) int   intx8;    // 32B fp8 operand (K=128)

union Frag8 { intx8 v; int4 q[2]; };

// ---------------- Kernel A: row sumsq, inv_norm, fp32 -> fp8(e4m3) quantize, zero accs ----
__global__ __launch_bounds__(256) void prep_kernel(
    const float* __restrict__ cb, unsigned char* __restrict__ cb_q,
    float* __restrict__ sq, float* __restrict__ inv_norm,
    unsigned* __restrict__ zero_base, int zero_len,
    int N, int d)
{
    const int gi = blockIdx.x * 256 + threadIdx.x;
    if (gi < zero_len) zero_base[gi] = 0u;

    const int row = blockIdx.x;
    const float* src = cb + (size_t)row * d;
    unsigned char* dst = cb_q + (size_t)row * d;
    const int t = threadIdx.x;

    float s = 0.f;
    for (int c = t * 4; c < d; c += 1024) {
        float4 v = *(const float4*)(src + c);
        s += v.x * v.x + v.y * v.y + v.z * v.z + v.w * v.w;
        int pk = __builtin_amdgcn_cvt_pk_fp8_f32(v.x, v.y, 0, false);   // bytes 0,1
        pk     = __builtin_amdgcn_cvt_pk_fp8_f32(v.z, v.w, pk, true);   // bytes 2,3
        *(int*)(dst + c) = pk;
    }
    for (int o = 32; o > 0; o >>= 1) s += __shfl_down(s, o, 64);
    __shared__ float wsum[4];
    if ((t & 63) == 0) wsum[t >> 6] = s;
    __syncthreads();
    if (t == 0) {
        float tot = wsum[0] + wsum[1] + wsum[2] + wsum[3];
        sq[row] = tot;
        inv_norm[row] = rsqrtf(tot);
    }
}

// ---------------- Kernel B: fused symmetric MX-fp8 Gram GEMM + loss epilogue + finalize ----
// R16: LDS-FREE K-LOOP. Prior structure (R15, 150us) was latency-bound: global_load_lds
// -> __syncthreads -> vmcnt(0) drain per K-step parked ALL resident waves (MfmaUtil 9%,
// VALUBusy 12%, SIMDs idle ~75%). The fp8 matrix is 8 MB and (with the XCD-contiguous
// tile swizzle) each XCD strip is L2-resident; a block's A rows per K-step (16KB) fit L1.
// So: load each lane's MFMA fragment (2x16B at row*d + kt*128 + g*32) STRAIGHT from
// global into VGPRs — no LDS, no barriers, no vmcnt(0) in the loop. Explicit two-deep
// named fragment double-buffer (rule #20: static indexing) keeps 16 loads in flight
// under each K-step's ~550-cycle MFMA phase. VGPR ~220 -> (256,2).
// Established DO-NOTs: 64KB LDS dbuf (R9), 32KB LDS dbuf (R11), per-thread fences (R3),
// (256,4)+MX (R10 spills), 32x32x64 MX (R6), 1-wave blocks (R14).
__global__ __launch_bounds__(256, 2) void gram_loss_kernel(
    const unsigned char* __restrict__ A,   // N x d fp8
    const float* __restrict__ sq, const float* __restrict__ inv_norm,
    const int* __restrict__ starts, const int* __restrict__ ends,
    const int* __restrict__ max_ip,
    float* __restrict__ pos_acc, float* __restrict__ neg_acc,
    unsigned* __restrict__ counter, float* __restrict__ out,
    int N, int d)
{
    const int M = min(N, max_ip[0] + 1);

    // XCD-aware remap: contiguous tile ranges per XCD (nBlocks divisible by 8).
    int vt = blockIdx.x;
    const int nB = gridDim.x;
    if ((nB & 7) == 0) {
        const int per = nB >> 3;
        vt = (blockIdx.x & 7) * per + (blockIdx.x >> 3);
    }

    // triangular decode: vt -> (by, bx), by <= bx
    int bx = (int)((sqrtf(8.f * (float)vt + 1.f) - 1.f) * 0.5f);
    while ((bx + 1) * (bx + 2) / 2 <= vt) bx++;
    while (bx * (bx + 1) / 2 > vt) bx--;
    const int by = vt - bx * (bx + 1) / 2;

    const int rowBase = by * 128;
    const int colBase = bx * 128;
    const bool isDiag = (by == bx);

    const int tid  = threadIdx.x;
    const int wave = tid >> 6;
    const int lane = tid & 63;
    const int wr = (wave >> 1) * 64;
    const int wc = (wave & 1) * 64;

    floatx4 acc[4][4];
#pragma unroll
    for (int a = 0; a < 4; ++a)
#pragma unroll
        for (int b = 0; b < 4; ++b) acc[a][b] = (floatx4){0.f, 0.f, 0.f, 0.f};

    // fragment geometry: lane (rl, g) holds row (base + t4*16 + rl), k-bytes g*32..g*32+31
    const int rl = lane & 15;
    const int g  = lane >> 4;       // 0..3 (k-group)

    const unsigned char* aRow0 = A + (size_t)(rowBase + wr + rl) * d + g * 32;
    const unsigned char* bRow0 = A + (size_t)(colBase + wc + rl) * d + g * 32;
    const size_t rstep = (size_t)16 * d;   // t4 row stride

    const int kTiles = d / 128;            // 8

    Frag8 aX[4], bX[4], aY[4], bY[4];

#define LOADF(AF, BF, KOFF)                                                  \
    { _Pragma("unroll")                                                      \
      for (int t4 = 0; t4 < 4; ++t4) {                                       \
        const unsigned char* pa = aRow0 + (size_t)t4 * rstep + (KOFF);       \
        const unsigned char* pb = bRow0 + (size_t)t4 * rstep + (KOFF);       \
        AF[t4].q[0] = *(const int4*)(pa);                                    \
        AF[t4].q[1] = *(const int4*)(pa + 16);                               \
        BF[t4].q[0] = *(const int4*)(pb);                                    \
        BF[t4].q[1] = *(const int4*)(pb + 16);                               \
      } }

#define MFMAS(AF, BF)                                                        \
    { _Pragma("unroll")                                                      \
      for (int rt = 0; rt < 4; ++rt)                                         \
        _Pragma("unroll")                                                    \
        for (int ct = 0; ct < 4; ++ct)                                       \
          acc[rt][ct] = __builtin_amdgcn_mfma_scale_f32_16x16x128_f8f6f4(    \
              AF[rt].v, BF[ct].v, acc[rt][ct], 0, 0, 0, 127, 0, 127); }

    LOADF(aX, bX, 0)
    int kt = 0;
    for (;;) {
        if (kt + 1 < kTiles) LOADF(aY, bY, (kt + 1) * 128)
        MFMAS(aX, bX)
        ++kt; if (kt >= kTiles) break;
        if (kt + 1 < kTiles) LOADF(aX, bX, (kt + 1) * 128)
        MFMAS(aY, bY)
        ++kt; if (kt >= kTiles) break;
    }
#undef LOADF
#undef MFMAS

    // ---- epilogue (16x16 C/D: col=lane&15, row=(lane>>4)*4+reg) ----
    const int q  = lane >> 4;
    const int jlo = colBase + wc;
    const int ilo = rowBase + wr;

    int   jn[4];
    float jinv[4];
    bool  jvalid[4];
#pragma unroll
    for (int ct = 0; ct < 4; ++ct) {
        const int j = jlo + ct * 16 + rl;
        jn[ct]  = j;
        jinv[ct] = inv_norm[j];
        jvalid[ct] = (j < M);
    }

    // wave-uniform positive-pair possibility check
    bool posLane = false;
    {
        const int ri = ilo + lane;
        if (ri < M) posLane |= (ends[ri] >= jlo) && (starts[ri] <= jlo + 63);
        if (!isDiag) {
            const int cj = jlo + lane;
            if (cj < M) posLane |= (ends[cj] >= ilo) && (starts[cj] <= ilo + 63);
        }
    }
    const bool fullPath = (__ballot(posLane) != 0ULL);

    float posc[4] = {0.f, 0.f, 0.f, 0.f};
    float negc[4] = {0.f, 0.f, 0.f, 0.f};

    if (fullPath) {
        int   jns[4], jne[4];
        float jsq[4];
#pragma unroll
        for (int ct = 0; ct < 4; ++ct) {
            jsq[ct] = sq[jn[ct]];
            jns[ct] = jvalid[ct] ? starts[jn[ct]] : 0;
            jne[ct] = jvalid[ct] ? ends[jn[ct]]   : -1;
        }
#pragma unroll
        for (int rt = 0; rt < 4; ++rt) {
            const int ibase = ilo + rt * 16 + q * 4;
#pragma unroll
            for (int reg = 0; reg < 4; ++reg) {
                const int i = ibase + reg;
                const bool rowValid = (i < M);
                const int ns = rowValid ? starts[i] : 0;
                const int ne = rowValid ? ends[i]   : -1;
                const float iinv = inv_norm[i];
                const float isq  = sq[i];
                float posp = 0.f, negp = 0.f;
#pragma unroll
                for (int ct = 0; ct < 4; ++ct) {
                    const float dot = acc[rt][ct][reg];
                    const int j = jn[ct];
                    float cosv = dot * iinv * jinv[ct];
                    cosv = fminf(fmaxf(cosv, -1.f), 1.f);
                    float tn = fmaxf(fabsf(cosv) - M_NEG, 0.f);
                    const float nterm = tn * tn;
                    const float d2 = fmaxf(isq + jsq[ct] - 2.f * dot, 0.f);
                    float tp = fmaxf(sqrtf(d2) - M_POS, 0.f);
                    const float pterm = tp * tp;
                    const bool dg = (j == i);
                    if (rowValid) {
                        const bool in_r = (j >= ns) && (j <= ne);
                        if (in_r && !dg) posp += pterm;
                        if (!in_r || dg) negp += nterm;
                    }
                    if (!isDiag && jvalid[ct]) {
                        const bool in_c = (i >= jns[ct]) && (i <= jne[ct]);
                        if (in_c && !dg) posc[ct] += pterm;
                        if (!in_c || dg) negc[ct] += nterm;
                    }
                }
#pragma unroll
                for (int m = 1; m < 16; m <<= 1) {
                    posp += __shfl_xor(posp, m, 64);
                    negp += __shfl_xor(negp, m, 64);
                }
                if (rowValid && rl == 0) {
                    atomicAdd(&pos_acc[i], posp);
                    atomicAdd(&neg_acc[i], negp);
                }
            }
        }
        if (!isDiag) {
#pragma unroll
            for (int ct = 0; ct < 4; ++ct) {
                posc[ct] += __shfl_xor(posc[ct], 16, 64);
                posc[ct] += __shfl_xor(posc[ct], 32, 64);
                negc[ct] += __shfl_xor(negc[ct], 16, 64);
                negc[ct] += __shfl_xor(negc[ct], 32, 64);
            }
            if (q == 0) {
#pragma unroll
                for (int ct = 0; ct < 4; ++ct) {
                    if (jvalid[ct]) {
                        atomicAdd(&pos_acc[jn[ct]], posc[ct]);
                        atomicAdd(&neg_acc[jn[ct]], negc[ct]);
                    }
                }
            }
        }
    } else {
        // fast path: every element is a negative for both its row and its column
#pragma unroll
        for (int rt = 0; rt < 4; ++rt) {
            const int ibase = ilo + rt * 16 + q * 4;
#pragma unroll
            for (int reg = 0; reg < 4; ++reg) {
                const int i = ibase + reg;
                const float iinv = inv_norm[i];
                float negp = 0.f;
#pragma unroll
                for (int ct = 0; ct < 4; ++ct) {
                    const float dot = acc[rt][ct][reg];
                    float cosv = dot * iinv * jinv[ct];
                    cosv = fminf(fmaxf(cosv, -1.f), 1.f);
                    float tn = fmaxf(fabsf(cosv) - M_NEG, 0.f);
                    const float nterm = tn * tn;
                    negp += nterm;
                    negc[ct] += nterm;
                }
#pragma unroll
                for (int m = 1; m < 16; m <<= 1)
                    negp += __shfl_xor(negp, m, 64);
                if ((i < M) && rl == 0)
                    atomicAdd(&neg_acc[i], negp);
            }
        }
        if (!isDiag) {
#pragma unroll
            for (int ct = 0; ct < 4; ++ct) {
                negc[ct] += __shfl_xor(negc[ct], 16, 64);
                negc[ct] += __shfl_xor(negc[ct], 32, 64);
            }
            if (q == 0) {
#pragma unroll
                for (int ct = 0; ct < 4; ++ct)
                    if (jvalid[ct])
                        atomicAdd(&neg_acc[jn[ct]], negc[ct]);
            }
        }
    }

    // ---- last-block finalize (fence/atomic by tid0 only — validated R7) ----
    __shared__ bool amLast;
    __syncthreads();
    if (tid == 0) {
        __threadfence();
        unsigned old = atomicAdd(counter, 1u);
        amLast = (old == (unsigned)(gridDim.x - 1));
    }
    __syncthreads();
    if (amLast) {
        __threadfence();
        float total = 0.f;
        int cnt = 0;
        for (int i = tid; i < M; i += 256) {
            const float pa = __hip_atomic_load(&pos_acc[i], __ATOMIC_RELAXED, __HIP_MEMORY_SCOPE_AGENT);
            const float na = __hip_atomic_load(&neg_acc[i], __ATOMIC_RELAXED, __HIP_MEMORY_SCOPE_AGENT);
            const int ns = starts[i], ne = ends[i];
            const int lo = max(ns, 0), hi = min(ne, N - 1);
            const int inr = max(hi - lo + 1, 0);
            const bool dg = (i >= ns) && (i <= ne);
            const int pos_cnt = inr - (dg ? 1 : 0);
            const int neg_cnt = N - inr + (dg ? 1 : 0);
            if (pos_cnt > 0 && neg_cnt > 0) {
                total += pa / (float)max(pos_cnt, 1)
                       + LAM_NEG * na / (float)max(neg_cnt, 1);
                cnt++;
            }
        }
        for (int o = 32; o > 0; o >>= 1) {
            total += __shfl_down(total, o, 64);
            cnt   += __shfl_down(cnt, o, 64);
        }
        __shared__ float fin_ts[4];
        __shared__ int   fin_cs[4];
        if ((tid & 63) == 0) { fin_ts[tid >> 6] = total; fin_cs[tid >> 6] = cnt; }
        __syncthreads();
        if (tid == 0) {
            float T = fin_ts[0] + fin_ts[1] + fin_ts[2] + fin_ts[3];
            int   C = fin_cs[0] + fin_cs[1] + fin_cs[2] + fin_cs[3];
            out[0] = (C > 0) ? T / (float)C : 0.f;
        }
    }
}

extern "C" void kernel_launch(void* const* d_in, const int* in_sizes, int n_in,
                              void* d_out, int out_size, void* d_ws, size_t ws_size,
                              hipStream_t stream) {
    const float* cb     = (const float*)d_in[0];
    const int*   starts = (const int*)d_in[1];
    const int*   ends   = (const int*)d_in[2];
    const int*   max_ip = (const int*)d_in[3];
    float* out = (float*)d_out;

    const int N = in_sizes[1];
    const int d = in_sizes[0] / N;

    char* ws = (char*)d_ws;
    unsigned char* cb_q = (unsigned char*)ws;
    size_t off = ((size_t)N * d + 255) & ~(size_t)255;
    float* sq       = (float*)(ws + off); off += (size_t)N * 4;
    float* inv_norm = (float*)(ws + off); off += (size_t)N * 4;
    float* pos_acc  = (float*)(ws + off); off += (size_t)N * 4;
    float* neg_acc  = (float*)(ws + off); off += (size_t)N * 4;
    unsigned* counter = (unsigned*)(ws + off); off += 256;

    // prep zeroes pos_acc/neg_acc/counter (2N+1 u32, contiguous)
    prep_kernel<<<N, 256, 0, stream>>>(cb, cb_q, sq, inv_norm,
                                       (unsigned*)pos_acc, 2 * N + 1, N, d);

    const int nb = N / 128;
    const int nBlocks = nb * (nb + 1) / 2;   // upper-triangular tiles
    gram_loss_kernel<<<nBlocks, 256, 0, stream>>>(cb_q, sq, inv_norm, starts, ends,
                                                  max_ip, pos_acc, neg_acc, counter,
                                                  out, N, d);
}

// Round 2
// 232.240 us; speedup vs baseline: 1.2418x; 1.2418x over previous
//
#include <hip/hip_runtime.h>
#include <hip/hip_bf16.h>
#include <stdint.h>

#define M_POS 0.5f
#define M_NEG 0.1f
#define LAM_NEG 1.0f

typedef __attribute__((ext_vector_type(4))) float floatx4;  // 16x16 MFMA accumulator
typedef __attribute__((ext_vector_type(8))) int   intx8;    // 32B fp8 operand (K=128)

union Frag8 { intx8 v; int4 q[2]; };

// ---------------- Kernel A: row sumsq, inv_norm, fp32 -> fp8(e4m3) quantize, zero accs ----
__global__ __launch_bounds__(256) void prep_kernel(
    const float* __restrict__ cb, unsigned char* __restrict__ cb_q,
    float* __restrict__ sq, float* __restrict__ inv_norm,
    unsigned* __restrict__ zero_base, int zero_len,
    int N, int d)
{
    const int gi = blockIdx.x * 256 + threadIdx.x;
    if (gi < zero_len) zero_base[gi] = 0u;

    const int row = blockIdx.x;
    const float* src = cb + (size_t)row * d;
    unsigned char* dst = cb_q + (size_t)row * d;
    const int t = threadIdx.x;

    float s = 0.f;
    for (int c = t * 4; c < d; c += 1024) {
        float4 v = *(const float4*)(src + c);
        s += v.x * v.x + v.y * v.y + v.z * v.z + v.w * v.w;
        int pk = __builtin_amdgcn_cvt_pk_fp8_f32(v.x, v.y, 0, false);   // bytes 0,1
        pk     = __builtin_amdgcn_cvt_pk_fp8_f32(v.z, v.w, pk, true);   // bytes 2,3
        *(int*)(dst + c) = pk;
    }
    for (int o = 32; o > 0; o >>= 1) s += __shfl_down(s, o, 64);
    __shared__ float wsum[4];
    if ((t & 63) == 0) wsum[t >> 6] = s;
    __syncthreads();
    if (t == 0) {
        float tot = wsum[0] + wsum[1] + wsum[2] + wsum[3];
        sq[row] = tot;
        inv_norm[row] = rsqrtf(tot);
    }
}

// ---------------- Kernel B: fused symmetric MX-fp8 Gram GEMM + loss epilogue + finalize ----
// R17 = R15's staging (coalesced global_load_lds + xor-swizzle, verified) + DOUBLE-BUFFER
// LDS with COUNTED-WAIT 2-PHASE SCHEDULE (guide T3/T4 minimum recipe). R15's stall was
// structural: stage -> __syncthreads (implicit vmcnt(0) drain) with no compute in between
// parked every wave on full L2 latency each K-step (MfmaUtil 9%). Here each iteration:
//   STAGE(buf^1, kt+1)  -> ds_read(buf) + 16 MFMA  -> s_waitcnt vmcnt(0) -> s_barrier
// so the 8 staging loads have the whole MFMA phase (~550cy) in flight before the wait.
// No __syncthreads in the loop (raw s_barrier; compiler handles lgkmcnt for ds_read->MFMA).
// DO-NOTs: R16 direct-global fragment loads (1KB-stride fan-out, 32 lines/instr: 218us,
// MfmaUtil 6%, FETCH +37%); R9/R11 dbuf-with-__syncthreads-drain (no counted waits -> no
// overlap, pure occupancy loss); per-thread fences (R3); (256,4)+MX spills (R10);
// 32x32x64 MX (R6); 1-wave blocks (R14). T5 setprio skipped: null at 2-phase (regime gate).
__global__ __launch_bounds__(256, 2) void gram_loss_kernel(
    const unsigned char* __restrict__ A,   // N x d fp8
    const float* __restrict__ sq, const float* __restrict__ inv_norm,
    const int* __restrict__ starts, const int* __restrict__ ends,
    const int* __restrict__ max_ip,
    float* __restrict__ pos_acc, float* __restrict__ neg_acc,
    unsigned* __restrict__ counter, float* __restrict__ out,
    int N, int d)
{
    const int M = min(N, max_ip[0] + 1);

    // XCD-aware remap: contiguous tile ranges per XCD (nBlocks divisible by 8).
    int vt = blockIdx.x;
    const int nB = gridDim.x;
    if ((nB & 7) == 0) {
        const int per = nB >> 3;
        vt = (blockIdx.x & 7) * per + (blockIdx.x >> 3);
    }

    // triangular decode: vt -> (by, bx), by <= bx
    int bx = (int)((sqrtf(8.f * (float)vt + 1.f) - 1.f) * 0.5f);
    while ((bx + 1) * (bx + 2) / 2 <= vt) bx++;
    while (bx * (bx + 1) / 2 > vt) bx--;
    const int by = vt - bx * (bx + 1) / 2;

    const int rowBase = by * 128;
    const int colBase = bx * 128;
    const bool isDiag = (by == bx);

    __shared__ alignas(16) unsigned char ldsA[2][128 * 128];
    __shared__ alignas(16) unsigned char ldsB[2][128 * 128];

    const int tid  = threadIdx.x;
    const int wave = tid >> 6;
    const int lane = tid & 63;
    const int wr = (wave >> 1) * 64;
    const int wc = (wave & 1) * 64;

    floatx4 acc[4][4];
#pragma unroll
    for (int a = 0; a < 4; ++a)
#pragma unroll
        for (int b = 0; b < 4; ++b) acc[a][b] = (floatx4){0.f, 0.f, 0.f, 0.f};

    // staging: per issue, 8 rows x 8 chunks; dst lane-linear; src chunk xor lane-constant.
    const int sRow = lane >> 3;                         // 0..7
    const int sChk = lane & 7;                          // 16B chunk 0..7
    const int srcOffC = ((sChk ^ sRow) * 16);
    const int kTiles = d / 128;                         // 8

    // fragment-read constants: lane holds k = (lane>>4)*32 .. +31 of its row
    const int rl = lane & 15;
    const int g  = lane >> 4;       // 0..3 (k-group)
    const int rx = rl & 7;
    const int c0 = (((2 * g)     ^ rx) * 16);
    const int c1 = (((2 * g + 1) ^ rx) * 16);

#define STAGE(BUF, KT)                                                          \
    { const int k0_ = (KT) * 128;                                               \
      _Pragma("unroll")                                                         \
      for (int h = 0; h < 4; ++h) {                                             \
        const int r_ = wave * 32 + h * 8 + sRow;                                \
        const unsigned char* ga_ = A + (size_t)(rowBase + r_) * d + k0_ + srcOffC; \
        const unsigned char* gb_ = A + (size_t)(colBase + r_) * d + k0_ + srcOffC; \
        __builtin_amdgcn_global_load_lds(                                       \
            (const __attribute__((address_space(1))) void*)ga_,                 \
            (__attribute__((address_space(3))) void*)(ldsA[BUF] + r_ * 128 + sChk * 16), 16, 0, 0); \
        __builtin_amdgcn_global_load_lds(                                       \
            (const __attribute__((address_space(1))) void*)gb_,                 \
            (__attribute__((address_space(3))) void*)(ldsB[BUF] + r_ * 128 + sChk * 16), 16, 0, 0); \
      } }

    // prologue: stage tile 0, drain, barrier
    STAGE(0, 0)
    asm volatile("s_waitcnt vmcnt(0)" ::: "memory");
    __builtin_amdgcn_s_barrier();

    int cur = 0;
    for (int kt = 0; kt < kTiles; ++kt) {
        const bool more = (kt + 1 < kTiles);
        if (more) {
            if (cur == 0) STAGE(1, kt + 1)
            else          STAGE(0, kt + 1)
        }

        Frag8 af[4], bf[4];
#pragma unroll
        for (int t4 = 0; t4 < 4; ++t4) {
            const unsigned char* pa = ldsA[cur] + (wr + t4 * 16 + rl) * 128;
            af[t4].q[0] = *(const int4*)(pa + c0);
            af[t4].q[1] = *(const int4*)(pa + c1);
            const unsigned char* pb = ldsB[cur] + (wc + t4 * 16 + rl) * 128;
            bf[t4].q[0] = *(const int4*)(pb + c0);
            bf[t4].q[1] = *(const int4*)(pb + c1);
        }
#pragma unroll
        for (int rt = 0; rt < 4; ++rt)
#pragma unroll
            for (int ct = 0; ct < 4; ++ct)
                acc[rt][ct] = __builtin_amdgcn_mfma_scale_f32_16x16x128_f8f6f4(
                    af[rt].v, bf[ct].v, acc[rt][ct], 0, 0, 0, 127, 0, 127);

        if (more) {
            // own 8 staging loads were issued a full MFMA-phase ago: counted drain now,
            // then barrier hands the freshly staged buffer to all waves.
            asm volatile("s_waitcnt vmcnt(0)" ::: "memory");
            __builtin_amdgcn_s_barrier();
            cur ^= 1;
        }
    }
#undef STAGE

    // ---- epilogue (16x16 C/D: col=lane&15, row=(lane>>4)*4+reg) ----
    const int q  = lane >> 4;
    const int jlo = colBase + wc;
    const int ilo = rowBase + wr;

    int   jn[4];
    float jinv[4];
    bool  jvalid[4];
#pragma unroll
    for (int ct = 0; ct < 4; ++ct) {
        const int j = jlo + ct * 16 + rl;
        jn[ct]  = j;
        jinv[ct] = inv_norm[j];
        jvalid[ct] = (j < M);
    }

    // wave-uniform positive-pair possibility check
    bool posLane = false;
    {
        const int ri = ilo + lane;
        if (ri < M) posLane |= (ends[ri] >= jlo) && (starts[ri] <= jlo + 63);
        if (!isDiag) {
            const int cj = jlo + lane;
            if (cj < M) posLane |= (ends[cj] >= ilo) && (starts[cj] <= ilo + 63);
        }
    }
    const bool fullPath = (__ballot(posLane) != 0ULL);

    float posc[4] = {0.f, 0.f, 0.f, 0.f};
    float negc[4] = {0.f, 0.f, 0.f, 0.f};

    if (fullPath) {
        int   jns[4], jne[4];
        float jsq[4];
#pragma unroll
        for (int ct = 0; ct < 4; ++ct) {
            jsq[ct] = sq[jn[ct]];
            jns[ct] = jvalid[ct] ? starts[jn[ct]] : 0;
            jne[ct] = jvalid[ct] ? ends[jn[ct]]   : -1;
        }
#pragma unroll
        for (int rt = 0; rt < 4; ++rt) {
            const int ibase = ilo + rt * 16 + q * 4;
#pragma unroll
            for (int reg = 0; reg < 4; ++reg) {
                const int i = ibase + reg;
                const bool rowValid = (i < M);
                const int ns = rowValid ? starts[i] : 0;
                const int ne = rowValid ? ends[i]   : -1;
                const float iinv = inv_norm[i];
                const float isq  = sq[i];
                float posp = 0.f, negp = 0.f;
#pragma unroll
                for (int ct = 0; ct < 4; ++ct) {
                    const float dot = acc[rt][ct][reg];
                    const int j = jn[ct];
                    float cosv = dot * iinv * jinv[ct];
                    cosv = fminf(fmaxf(cosv, -1.f), 1.f);
                    float tn = fmaxf(fabsf(cosv) - M_NEG, 0.f);
                    const float nterm = tn * tn;
                    const float d2 = fmaxf(isq + jsq[ct] - 2.f * dot, 0.f);
                    float tp = fmaxf(sqrtf(d2) - M_POS, 0.f);
                    const float pterm = tp * tp;
                    const bool dg = (j == i);
                    if (rowValid) {
                        const bool in_r = (j >= ns) && (j <= ne);
                        if (in_r && !dg) posp += pterm;
                        if (!in_r || dg) negp += nterm;
                    }
                    if (!isDiag && jvalid[ct]) {
                        const bool in_c = (i >= jns[ct]) && (i <= jne[ct]);
                        if (in_c && !dg) posc[ct] += pterm;
                        if (!in_c || dg) negc[ct] += nterm;
                    }
                }
#pragma unroll
                for (int m = 1; m < 16; m <<= 1) {
                    posp += __shfl_xor(posp, m, 64);
                    negp += __shfl_xor(negp, m, 64);
                }
                if (rowValid && rl == 0) {
                    atomicAdd(&pos_acc[i], posp);
                    atomicAdd(&neg_acc[i], negp);
                }
            }
        }
        if (!isDiag) {
#pragma unroll
            for (int ct = 0; ct < 4; ++ct) {
                posc[ct] += __shfl_xor(posc[ct], 16, 64);
                posc[ct] += __shfl_xor(posc[ct], 32, 64);
                negc[ct] += __shfl_xor(negc[ct], 16, 64);
                negc[ct] += __shfl_xor(negc[ct], 32, 64);
            }
            if (q == 0) {
#pragma unroll
                for (int ct = 0; ct < 4; ++ct) {
                    if (jvalid[ct]) {
                        atomicAdd(&pos_acc[jn[ct]], posc[ct]);
                        atomicAdd(&neg_acc[jn[ct]], negc[ct]);
                    }
                }
            }
        }
    } else {
        // fast path: every element is a negative for both its row and its column
#pragma unroll
        for (int rt = 0; rt < 4; ++rt) {
            const int ibase = ilo + rt * 16 + q * 4;
#pragma unroll
            for (int reg = 0; reg < 4; ++reg) {
                const int i = ibase + reg;
                const float iinv = inv_norm[i];
                float negp = 0.f;
#pragma unroll
                for (int ct = 0; ct < 4; ++ct) {
                    const float dot = acc[rt][ct][reg];
                    float cosv = dot * iinv * jinv[ct];
                    cosv = fminf(fmaxf(cosv, -1.f), 1.f);
                    float tn = fmaxf(fabsf(cosv) - M_NEG, 0.f);
                    const float nterm = tn * tn;
                    negp += nterm;
                    negc[ct] += nterm;
                }
#pragma unroll
                for (int m = 1; m < 16; m <<= 1)
                    negp += __shfl_xor(negp, m, 64);
                if ((i < M) && rl == 0)
                    atomicAdd(&neg_acc[i], negp);
            }
        }
        if (!isDiag) {
#pragma unroll
            for (int ct = 0; ct < 4; ++ct) {
                negc[ct] += __shfl_xor(negc[ct], 16, 64);
                negc[ct] += __shfl_xor(negc[ct], 32, 64);
            }
            if (q == 0) {
#pragma unroll
                for (int ct = 0; ct < 4; ++ct)
                    if (jvalid[ct])
                        atomicAdd(&neg_acc[jn[ct]], negc[ct]);
            }
        }
    }

    // ---- last-block finalize (fence/atomic by tid0 only — validated R7) ----
    __shared__ bool amLast;
    __syncthreads();
    if (tid == 0) {
        __threadfence();
        unsigned old = atomicAdd(counter, 1u);
        amLast = (old == (unsigned)(gridDim.x - 1));
    }
    __syncthreads();
    if (amLast) {
        __threadfence();
        float total = 0.f;
        int cnt = 0;
        for (int i = tid; i < M; i += 256) {
            const float pa = __hip_atomic_load(&pos_acc[i], __ATOMIC_RELAXED, __HIP_MEMORY_SCOPE_AGENT);
            const float na = __hip_atomic_load(&neg_acc[i], __ATOMIC_RELAXED, __HIP_MEMORY_SCOPE_AGENT);
            const int ns = starts[i], ne = ends[i];
            const int lo = max(ns, 0), hi = min(ne, N - 1);
            const int inr = max(hi - lo + 1, 0);
            const bool dg = (i >= ns) && (i <= ne);
            const int pos_cnt = inr - (dg ? 1 : 0);
            const int neg_cnt = N - inr + (dg ? 1 : 0);
            if (pos_cnt > 0 && neg_cnt > 0) {
                total += pa / (float)max(pos_cnt, 1)
                       + LAM_NEG * na / (float)max(neg_cnt, 1);
                cnt++;
            }
        }
        for (int o = 32; o > 0; o >>= 1) {
            total += __shfl_down(total, o, 64);
            cnt   += __shfl_down(cnt, o, 64);
        }
        __shared__ float fin_ts[4];
        __shared__ int   fin_cs[4];
        if ((tid & 63) == 0) { fin_ts[tid >> 6] = total; fin_cs[tid >> 6] = cnt; }
        __syncthreads();
        if (tid == 0) {
            float T = fin_ts[0] + fin_ts[1] + fin_ts[2] + fin_ts[3];
            int   C = fin_cs[0] + fin_cs[1] + fin_cs[2] + fin_cs[3];
            out[0] = (C > 0) ? T / (float)C : 0.f;
        }
    }
}

extern "C" void kernel_launch(void* const* d_in, const int* in_sizes, int n_in,
                              void* d_out, int out_size, void* d_ws, size_t ws_size,
                              hipStream_t stream) {
    const float* cb     = (const float*)d_in[0];
    const int*   starts = (const int*)d_in[1];
    const int*   ends   = (const int*)d_in[2];
    const int*   max_ip = (const int*)d_in[3];
    float* out = (float*)d_out;

    const int N = in_sizes[1];
    const int d = in_sizes[0] / N;

    char* ws = (char*)d_ws;
    unsigned char* cb_q = (unsigned char*)ws;
    size_t off = ((size_t)N * d + 255) & ~(size_t)255;
    float* sq       = (float*)(ws + off); off += (size_t)N * 4;
    float* inv_norm = (float*)(ws + off); off += (size_t)N * 4;
    float* pos_acc  = (float*)(ws + off); off += (size_t)N * 4;
    float* neg_acc  = (float*)(ws + off); off += (size_t)N * 4;
    unsigned* counter = (unsigned*)(ws + off); off += 256;

    // prep zeroes pos_acc/neg_acc/counter (2N+1 u32, contiguous)
    prep_kernel<<<N, 256, 0, stream>>>(cb, cb_q, sq, inv_norm,
                                       (unsigned*)pos_acc, 2 * N + 1, N, d);

    const int nb = N / 128;
    const int nBlocks = nb * (nb + 1) / 2;   // upper-triangular tiles
    gram_loss_kernel<<<nBlocks, 256, 0, stream>>>(cb_q, sq, inv_norm, starts, ends,
                                                  max_ip, pos_acc, neg_acc, counter,
                                                  out, N, d);
}

// Round 3
// 230.035 us; speedup vs baseline: 1.2537x; 1.0096x over previous
//
#include <hip/hip_runtime.h>
#include <hip/hip_bf16.h>
#include <stdint.h>

#define M_POS 0.5f
#define M_NEG 0.1f
#define LAM_NEG 1.0f

typedef __attribute__((ext_vector_type(4))) float floatx4;  // 16x16 MFMA accumulator
typedef __attribute__((ext_vector_type(8))) int   intx8;    // 32B fp8 operand (K=128)

union Frag8 { intx8 v; int4 q[2]; };

// Fragment-linear fp8 layout (R18): the quantized matrix is stored as MFMA fragments.
//   frag(R,K) = 2KB block at ((R*8 + K) << 11), R = row/16 (8 = d/128 kTiles)
//   within frag: byte = (h << 10) + (lane << 4) + off,  h = (k%32)/16, off = k%16,
//                lane = ((k%128)/32)*16 + row%16   (the 16x16x128 A/B operand mapping,
//                identical to what R15's verified LDS xor-swizzle handed each lane).
// A wave's fragment load is then TWO global_load_dwordx4 each reading 1KB fully dense.

// ---------------- Kernel A: row sumsq, inv_norm, fp32 -> fp8(e4m3) quantize, zero accs ----
__global__ __launch_bounds__(256) void prep_kernel(
    const float* __restrict__ cb, unsigned char* __restrict__ cb_q,
    float* __restrict__ sq, float* __restrict__ inv_norm,
    unsigned* __restrict__ zero_base, int zero_len,
    int N, int d)
{
    const int gi = blockIdx.x * 256 + threadIdx.x;
    if (gi < zero_len) zero_base[gi] = 0u;

    const int row = blockIdx.x;
    const float* src = cb + (size_t)row * d;
    const int t = threadIdx.x;
    const size_t fragRowBase = ((size_t)(row >> 4) * 8) << 11;  // frag(R,0)
    const int rl = row & 15;

    float s = 0.f;
    for (int c = t * 4; c < d; c += 1024) {
        float4 v = *(const float4*)(src + c);
        s += v.x * v.x + v.y * v.y + v.z * v.z + v.w * v.w;
        int pk = __builtin_amdgcn_cvt_pk_fp8_f32(v.x, v.y, 0, false);   // bytes 0,1
        pk     = __builtin_amdgcn_cvt_pk_fp8_f32(v.z, v.w, pk, true);   // bytes 2,3
        const int K = c >> 7;            // k-tile (128B)
        const int g = (c >> 5) & 3;      // 32B k-group within tile
        const int h = (c >> 4) & 1;      // 16B half within the lane's 32B
        unsigned char* dq = cb_q + fragRowBase + ((size_t)K << 11)
                          + (h << 10) + ((g * 16 + rl) << 4) + (c & 15);
        *(int*)dq = pk;
    }
    for (int o = 32; o > 0; o >>= 1) s += __shfl_down(s, o, 64);
    __shared__ float wsum[4];
    if ((t & 63) == 0) wsum[t >> 6] = s;
    __syncthreads();
    if (t == 0) {
        float tot = wsum[0] + wsum[1] + wsum[2] + wsum[3];
        sq[row] = tot;
        inv_norm[row] = rsqrtf(tot);
    }
}

// ---------------- Kernel B: fused symmetric MX-fp8 Gram GEMM + loss epilogue + finalize ----
// R18: FRAGMENT-LINEAR DIRECT LOADS. R15/R17 analysis: K-loop was transaction/latency
// bound, not BW bound (MfmaUtil 9%, HBM 6% peak; models say 25-50us, measured 150+).
// R16 proved direct-global frags fail when each instr fans to 32 lines; R17 proved the
// 2-phase drain is structural (m233). Fix: store cb_q AS fragments (prep writes them),
// so each operand load = 2x global_load_dwordx4, each 1KB DENSE. No LDS, no barriers,
// no drains in the K-loop — waves pipeline independently; named X/Y frag dbuf + 
// sched_barrier(0) pins prefetch-before-MFMA (R16's 112-VGPR showed compiler sinks it
// otherwise; expect ~200 VGPR if the pipeline survived).
// DO-NOTs: row-major direct frag loads (R16); dbuf-LDS both drain flavors (R9/R11/R17);
// per-thread fences (R3); (256,4)+MX spills (R10); 32x32x64 MX (R6); 1-wave blocks (R14).
__global__ __launch_bounds__(256, 2) void gram_loss_kernel(
    const unsigned char* __restrict__ A,   // N x d fp8, FRAGMENT-LINEAR layout
    const float* __restrict__ sq, const float* __restrict__ inv_norm,
    const int* __restrict__ starts, const int* __restrict__ ends,
    const int* __restrict__ max_ip,
    float* __restrict__ pos_acc, float* __restrict__ neg_acc,
    unsigned* __restrict__ counter, float* __restrict__ out,
    int N, int d)
{
    const int M = min(N, max_ip[0] + 1);

    // XCD-aware remap: contiguous tile ranges per XCD (nBlocks divisible by 8).
    int vt = blockIdx.x;
    const int nB = gridDim.x;
    if ((nB & 7) == 0) {
        const int per = nB >> 3;
        vt = (blockIdx.x & 7) * per + (blockIdx.x >> 3);
    }

    // triangular decode: vt -> (by, bx), by <= bx
    int bx = (int)((sqrtf(8.f * (float)vt + 1.f) - 1.f) * 0.5f);
    while ((bx + 1) * (bx + 2) / 2 <= vt) bx++;
    while (bx * (bx + 1) / 2 > vt) bx--;
    const int by = vt - bx * (bx + 1) / 2;

    const int rowBase = by * 128;
    const int colBase = bx * 128;
    const bool isDiag = (by == bx);

    const int tid  = threadIdx.x;
    const int wave = tid >> 6;
    const int lane = tid & 63;
    const int wr = (wave >> 1) * 64;
    const int wc = (wave & 1) * 64;

    floatx4 acc[4][4];
#pragma unroll
    for (int a = 0; a < 4; ++a)
#pragma unroll
        for (int b = 0; b < 4; ++b) acc[a][b] = (floatx4){0.f, 0.f, 0.f, 0.f};

    const int kTiles = d / 128;                         // 8
    const int rl = lane & 15;

    // fragment-linear operand bases: q0 at +lane*16, q1 at +1024+lane*16
    const unsigned char* aBase = A + ((((size_t)((rowBase + wr) >> 4)) * 8) << 11) + (lane << 4);
    const unsigned char* bBase = A + ((((size_t)((colBase + wc) >> 4)) * 8) << 11) + (lane << 4);

    Frag8 aX[4], bX[4], aY[4], bY[4];

#define LOADF(AF, BF, KT)                                                    \
    { _Pragma("unroll")                                                      \
      for (int t4 = 0; t4 < 4; ++t4) {                                       \
        const size_t off_ = ((size_t)(t4 * 8 + (KT))) << 11;                 \
        AF[t4].q[0] = *(const int4*)(aBase + off_);                          \
        AF[t4].q[1] = *(const int4*)(aBase + off_ + 1024);                   \
        BF[t4].q[0] = *(const int4*)(bBase + off_);                          \
        BF[t4].q[1] = *(const int4*)(bBase + off_ + 1024);                   \
      } }

#define MFMAS(AF, BF)                                                        \
    { _Pragma("unroll")                                                      \
      for (int rt = 0; rt < 4; ++rt)                                         \
        _Pragma("unroll")                                                    \
        for (int ct = 0; ct < 4; ++ct)                                       \
          acc[rt][ct] = __builtin_amdgcn_mfma_scale_f32_16x16x128_f8f6f4(    \
              AF[rt].v, BF[ct].v, acc[rt][ct], 0, 0, 0, 127, 0, 127); }

    LOADF(aX, bX, 0)
    int kt = 0;
    for (;;) {
        if (kt + 1 < kTiles) LOADF(aY, bY, kt + 1)
        __builtin_amdgcn_sched_barrier(0);   // pin prefetch issue BEFORE the MFMA cluster
        MFMAS(aX, bX)
        ++kt; if (kt >= kTiles) break;
        if (kt + 1 < kTiles) LOADF(aX, bX, kt + 1)
        __builtin_amdgcn_sched_barrier(0);
        MFMAS(aY, bY)
        ++kt; if (kt >= kTiles) break;
    }
#undef LOADF
#undef MFMAS

    // ---- epilogue (16x16 C/D: col=lane&15, row=(lane>>4)*4+reg) ----
    const int q  = lane >> 4;
    const int jlo = colBase + wc;
    const int ilo = rowBase + wr;

    int   jn[4];
    float jinv[4];
    bool  jvalid[4];
#pragma unroll
    for (int ct = 0; ct < 4; ++ct) {
        const int j = jlo + ct * 16 + rl;
        jn[ct]  = j;
        jinv[ct] = inv_norm[j];
        jvalid[ct] = (j < M);
    }

    // wave-uniform positive-pair possibility check
    bool posLane = false;
    {
        const int ri = ilo + lane;
        if (ri < M) posLane |= (ends[ri] >= jlo) && (starts[ri] <= jlo + 63);
        if (!isDiag) {
            const int cj = jlo + lane;
            if (cj < M) posLane |= (ends[cj] >= ilo) && (starts[cj] <= ilo + 63);
        }
    }
    const bool fullPath = (__ballot(posLane) != 0ULL);

    float posc[4] = {0.f, 0.f, 0.f, 0.f};
    float negc[4] = {0.f, 0.f, 0.f, 0.f};

    if (fullPath) {
        int   jns[4], jne[4];
        float jsq[4];
#pragma unroll
        for (int ct = 0; ct < 4; ++ct) {
            jsq[ct] = sq[jn[ct]];
            jns[ct] = jvalid[ct] ? starts[jn[ct]] : 0;
            jne[ct] = jvalid[ct] ? ends[jn[ct]]   : -1;
        }
#pragma unroll
        for (int rt = 0; rt < 4; ++rt) {
            const int ibase = ilo + rt * 16 + q * 4;
#pragma unroll
            for (int reg = 0; reg < 4; ++reg) {
                const int i = ibase + reg;
                const bool rowValid = (i < M);
                const int ns = rowValid ? starts[i] : 0;
                const int ne = rowValid ? ends[i]   : -1;
                const float iinv = inv_norm[i];
                const float isq  = sq[i];
                float posp = 0.f, negp = 0.f;
#pragma unroll
                for (int ct = 0; ct < 4; ++ct) {
                    const float dot = acc[rt][ct][reg];
                    const int j = jn[ct];
                    float cosv = dot * iinv * jinv[ct];
                    cosv = fminf(fmaxf(cosv, -1.f), 1.f);
                    float tn = fmaxf(fabsf(cosv) - M_NEG, 0.f);
                    const float nterm = tn * tn;
                    const float d2 = fmaxf(isq + jsq[ct] - 2.f * dot, 0.f);
                    float tp = fmaxf(sqrtf(d2) - M_POS, 0.f);
                    const float pterm = tp * tp;
                    const bool dg = (j == i);
                    if (rowValid) {
                        const bool in_r = (j >= ns) && (j <= ne);
                        if (in_r && !dg) posp += pterm;
                        if (!in_r || dg) negp += nterm;
                    }
                    if (!isDiag && jvalid[ct]) {
                        const bool in_c = (i >= jns[ct]) && (i <= jne[ct]);
                        if (in_c && !dg) posc[ct] += pterm;
                        if (!in_c || dg) negc[ct] += nterm;
                    }
                }
#pragma unroll
                for (int m = 1; m < 16; m <<= 1) {
                    posp += __shfl_xor(posp, m, 64);
                    negp += __shfl_xor(negp, m, 64);
                }
                if (rowValid && rl == 0) {
                    atomicAdd(&pos_acc[i], posp);
                    atomicAdd(&neg_acc[i], negp);
                }
            }
        }
        if (!isDiag) {
#pragma unroll
            for (int ct = 0; ct < 4; ++ct) {
                posc[ct] += __shfl_xor(posc[ct], 16, 64);
                posc[ct] += __shfl_xor(posc[ct], 32, 64);
                negc[ct] += __shfl_xor(negc[ct], 16, 64);
                negc[ct] += __shfl_xor(negc[ct], 32, 64);
            }
            if (q == 0) {
#pragma unroll
                for (int ct = 0; ct < 4; ++ct) {
                    if (jvalid[ct]) {
                        atomicAdd(&pos_acc[jn[ct]], posc[ct]);
                        atomicAdd(&neg_acc[jn[ct]], negc[ct]);
                    }
                }
            }
        }
    } else {
        // fast path: every element is a negative for both its row and its column
#pragma unroll
        for (int rt = 0; rt < 4; ++rt) {
            const int ibase = ilo + rt * 16 + q * 4;
#pragma unroll
            for (int reg = 0; reg < 4; ++reg) {
                const int i = ibase + reg;
                const float iinv = inv_norm[i];
                float negp = 0.f;
#pragma unroll
                for (int ct = 0; ct < 4; ++ct) {
                    const float dot = acc[rt][ct][reg];
                    float cosv = dot * iinv * jinv[ct];
                    cosv = fminf(fmaxf(cosv, -1.f), 1.f);
                    float tn = fmaxf(fabsf(cosv) - M_NEG, 0.f);
                    const float nterm = tn * tn;
                    negp += nterm;
                    negc[ct] += nterm;
                }
#pragma unroll
                for (int m = 1; m < 16; m <<= 1)
                    negp += __shfl_xor(negp, m, 64);
                if ((i < M) && rl == 0)
                    atomicAdd(&neg_acc[i], negp);
            }
        }
        if (!isDiag) {
#pragma unroll
            for (int ct = 0; ct < 4; ++ct) {
                negc[ct] += __shfl_xor(negc[ct], 16, 64);
                negc[ct] += __shfl_xor(negc[ct], 32, 64);
            }
            if (q == 0) {
#pragma unroll
                for (int ct = 0; ct < 4; ++ct)
                    if (jvalid[ct])
                        atomicAdd(&neg_acc[jn[ct]], negc[ct]);
            }
        }
    }

    // ---- last-block finalize (fence/atomic by tid0 only — validated R7) ----
    __shared__ bool amLast;
    __syncthreads();
    if (tid == 0) {
        __threadfence();
        unsigned old = atomicAdd(counter, 1u);
        amLast = (old == (unsigned)(gridDim.x - 1));
    }
    __syncthreads();
    if (amLast) {
        __threadfence();
        float total = 0.f;
        int cnt = 0;
        for (int i = tid; i < M; i += 256) {
            const float pa = __hip_atomic_load(&pos_acc[i], __ATOMIC_RELAXED, __HIP_MEMORY_SCOPE_AGENT);
            const float na = __hip_atomic_load(&neg_acc[i], __ATOMIC_RELAXED, __HIP_MEMORY_SCOPE_AGENT);
            const int ns = starts[i], ne = ends[i];
            const int lo = max(ns, 0), hi = min(ne, N - 1);
            const int inr = max(hi - lo + 1, 0);
            const bool dg = (i >= ns) && (i <= ne);
            const int pos_cnt = inr - (dg ? 1 : 0);
            const int neg_cnt = N - inr + (dg ? 1 : 0);
            if (pos_cnt > 0 && neg_cnt > 0) {
                total += pa / (float)max(pos_cnt, 1)
                       + LAM_NEG * na / (float)max(neg_cnt, 1);
                cnt++;
            }
        }
        for (int o = 32; o > 0; o >>= 1) {
            total += __shfl_down(total, o, 64);
            cnt   += __shfl_down(cnt, o, 64);
        }
        __shared__ float fin_ts[4];
        __shared__ int   fin_cs[4];
        if ((tid & 63) == 0) { fin_ts[tid >> 6] = total; fin_cs[tid >> 6] = cnt; }
        __syncthreads();
        if (tid == 0) {
            float T = fin_ts[0] + fin_ts[1] + fin_ts[2] + fin_ts[3];
            int   C = fin_cs[0] + fin_cs[1] + fin_cs[2] + fin_cs[3];
            out[0] = (C > 0) ? T / (float)C : 0.f;
        }
    }
}

extern "C" void kernel_launch(void* const* d_in, const int* in_sizes, int n_in,
                              void* d_out, int out_size, void* d_ws, size_t ws_size,
                              hipStream_t stream) {
    const float* cb     = (const float*)d_in[0];
    const int*   starts = (const int*)d_in[1];
    const int*   ends   = (const int*)d_in[2];
    const int*   max_ip = (const int*)d_in[3];
    float* out = (float*)d_out;

    const int N = in_sizes[1];
    const int d = in_sizes[0] / N;

    char* ws = (char*)d_ws;
    unsigned char* cb_q = (unsigned char*)ws;
    size_t off = ((size_t)N * d + 255) & ~(size_t)255;
    float* sq       = (float*)(ws + off); off += (size_t)N * 4;
    float* inv_norm = (float*)(ws + off); off += (size_t)N * 4;
    float* pos_acc  = (float*)(ws + off); off += (size_t)N * 4;
    float* neg_acc  = (float*)(ws + off); off += (size_t)N * 4;
    unsigned* counter = (unsigned*)(ws + off); off += 256;

    // prep zeroes pos_acc/neg_acc/counter (2N+1 u32, contiguous)
    prep_kernel<<<N, 256, 0, stream>>>(cb, cb_q, sq, inv_norm,
                                       (unsigned*)pos_acc, 2 * N + 1, N, d);

    const int nb = N / 128;
    const int nBlocks = nb * (nb + 1) / 2;   // upper-triangular tiles
    gram_loss_kernel<<<nBlocks, 256, 0, stream>>>(cb_q, sq, inv_norm, starts, ends,
                                                  max_ip, pos_acc, neg_acc, counter,
                                                  out, N, d);
}

// Round 4
// 225.514 us; speedup vs baseline: 1.2789x; 1.0200x over previous
//
#include <hip/hip_runtime.h>
#include <hip/hip_bf16.h>
#include <stdint.h>

#define M_POS 0.5f
#define M_NEG 0.1f
#define LAM_NEG 1.0f

typedef __attribute__((ext_vector_type(4))) float floatx4;  // 16x16 MFMA accumulator
typedef __attribute__((ext_vector_type(8))) int   intx8;    // 32B fp8 operand (K=128)
typedef __attribute__((ext_vector_type(4))) int   int32x4;

union Frag8 { intx8 v; int32x4 q[2]; };

// Fragment-linear fp8 layout (R18, verified absmax=0): cb_q stored as MFMA fragments.
//   frag(R,K) = 2KB block at ((R*kTiles + K) << 11), R = row/16, K = k/128
//   within frag: byte = (h << 10) + (lane << 4) + off,  h = (k%32)/16, off = k%16,
//                lane = ((k%128)/32)*16 + row%16   (16x16x128 A/B operand mapping)
// A wave's fragment load = two global_load_dwordx4, each reading 1KB fully dense.

// ---------------- Kernel A: row sumsq, inv_norm, fp32 -> fp8 quantize (fragment layout) ----
// R19: 4 rows/block, one wave per row, 16B store per lane (R18 did 4B scatter stores: slower).
__global__ __launch_bounds__(256) void prep_kernel(
    const float* __restrict__ cb, unsigned char* __restrict__ cb_q,
    float* __restrict__ sq, float* __restrict__ inv_norm,
    unsigned* __restrict__ zero_base, int zero_len,
    int N, int d)
{
    const int gi = blockIdx.x * 256 + threadIdx.x;
    if (gi < zero_len) zero_base[gi] = 0u;

    const int t = threadIdx.x;
    const int w = t >> 6, l = t & 63;
    const int row = blockIdx.x * 4 + w;
    if (row >= N) return;
    const int kTiles = d >> 7;
    const float* src = cb + (size_t)row * d;
    unsigned char* fragRow = cb_q + (((size_t)(row >> 4) * kTiles) << 11);
    const int rl = row & 15;

    float s = 0.f;
    for (int c = l * 16; c < d; c += 1024) {
        float4 v0 = *(const float4*)(src + c);
        float4 v1 = *(const float4*)(src + c + 4);
        float4 v2 = *(const float4*)(src + c + 8);
        float4 v3 = *(const float4*)(src + c + 12);
        s += v0.x*v0.x + v0.y*v0.y + v0.z*v0.z + v0.w*v0.w
           + v1.x*v1.x + v1.y*v1.y + v1.z*v1.z + v1.w*v1.w
           + v2.x*v2.x + v2.y*v2.y + v2.z*v2.z + v2.w*v2.w
           + v3.x*v3.x + v3.y*v3.y + v3.z*v3.z + v3.w*v3.w;
        int p0 = __builtin_amdgcn_cvt_pk_fp8_f32(v0.x, v0.y, 0, false);
        p0     = __builtin_amdgcn_cvt_pk_fp8_f32(v0.z, v0.w, p0, true);
        int p1 = __builtin_amdgcn_cvt_pk_fp8_f32(v1.x, v1.y, 0, false);
        p1     = __builtin_amdgcn_cvt_pk_fp8_f32(v1.z, v1.w, p1, true);
        int p2 = __builtin_amdgcn_cvt_pk_fp8_f32(v2.x, v2.y, 0, false);
        p2     = __builtin_amdgcn_cvt_pk_fp8_f32(v2.z, v2.w, p2, true);
        int p3 = __builtin_amdgcn_cvt_pk_fp8_f32(v3.x, v3.y, 0, false);
        p3     = __builtin_amdgcn_cvt_pk_fp8_f32(v3.z, v3.w, p3, true);
        int32x4 pk; pk.x = p0; pk.y = p1; pk.z = p2; pk.w = p3;
        const int K = c >> 7, g = (c >> 5) & 3, h = (c >> 4) & 1;
        *(int32x4*)(fragRow + ((size_t)K << 11) + (h << 10) + ((g * 16 + rl) << 4)) = pk;
    }
    for (int o = 32; o > 0; o >>= 1) s += __shfl_down(s, o, 64);
    if (l == 0) { sq[row] = s; inv_norm[row] = rsqrtf(s); }
}

// ---------------- Kernel B: fused symmetric MX-fp8 Gram GEMM + loss epilogue + finalize ----
// R19: ASM-FORCED PREFETCH PIPELINE on the fragment-linear layout. Diagnosis chain:
// R15/R17/R18 all ~150us, MfmaUtil ~9%. R18's VGPR=104 proved the compiler sinks builtin
// prefetch loads to their uses even with sched_barrier(0) -> only ~2 loads in flight per
// wave -> 8kt x 16 x ~500cy serial latency = ~64k cy/block = the entire runtime.
// Fix (HK/m214 precedent): issue the NEXT tile's 16 loads as inline-asm
// global_load_dwordx4 (SSA outputs the compiler can't sink past sched_barrier), then
// s_waitcnt vmcnt(16) — drains ONLY the current tile; next tile's 16 loads stay in
// flight under the ~550cy MFMA cluster. No LDS, no barriers in the K-loop.
// Canary: VGPR ~150-210 = pipeline alive; ~104 = defeated; >240 = spill.
// DO-NOTs: builtin-load prefetch (R18: sunk); row-major direct frags (R16: 32-line
// fan-out); LDS dbuf both drain flavors (R9/R11/R17); per-thread fences (R3);
// (256,4)+MX spills (R10); 32x32x64 MX (R6); 1-wave blocks (R14).
__global__ __launch_bounds__(256, 2) void gram_loss_kernel(
    const unsigned char* __restrict__ A,   // N x d fp8, FRAGMENT-LINEAR layout
    const float* __restrict__ sq, const float* __restrict__ inv_norm,
    const int* __restrict__ starts, const int* __restrict__ ends,
    const int* __restrict__ max_ip,
    float* __restrict__ pos_acc, float* __restrict__ neg_acc,
    unsigned* __restrict__ counter, float* __restrict__ out,
    int N, int d)
{
    const int M = min(N, max_ip[0] + 1);

    // XCD-aware remap: contiguous tile ranges per XCD (nBlocks divisible by 8).
    int vt = blockIdx.x;
    const int nB = gridDim.x;
    if ((nB & 7) == 0) {
        const int per = nB >> 3;
        vt = (blockIdx.x & 7) * per + (blockIdx.x >> 3);
    }

    // triangular decode: vt -> (by, bx), by <= bx
    int bx = (int)((sqrtf(8.f * (float)vt + 1.f) - 1.f) * 0.5f);
    while ((bx + 1) * (bx + 2) / 2 <= vt) bx++;
    while (bx * (bx + 1) / 2 > vt) bx--;
    const int by = vt - bx * (bx + 1) / 2;

    const int rowBase = by * 128;
    const int colBase = bx * 128;
    const bool isDiag = (by == bx);

    const int tid  = threadIdx.x;
    const int wave = tid >> 6;
    const int lane = tid & 63;
    const int wr = (wave >> 1) * 64;
    const int wc = (wave & 1) * 64;

    floatx4 acc[4][4];
#pragma unroll
    for (int a = 0; a < 4; ++a)
#pragma unroll
        for (int b = 0; b < 4; ++b) acc[a][b] = (floatx4){0.f, 0.f, 0.f, 0.f};

    const int kTiles = d / 128;                         // 8
    const int rl = lane & 15;

    // fragment-linear operand bases: q0 at +lane*16, q1 at +1024+lane*16
    const unsigned char* aBase = A + ((((size_t)((rowBase + wr) >> 4)) * kTiles) << 11) + (lane << 4);
    const unsigned char* bBase = A + ((((size_t)((colBase + wc) >> 4)) * kTiles) << 11) + (lane << 4);

    Frag8 aX[4], bX[4], aY[4], bY[4];

#define GL0(dst, p)  asm volatile("global_load_dwordx4 %0, %1, off"             : "=v"(dst) : "v"(p))
#define GL1(dst, p)  asm volatile("global_load_dwordx4 %0, %1, off offset:1024" : "=v"(dst) : "v"(p))

#define ISSUE(AF, BF, KT)                                                        \
    { _Pragma("unroll")                                                          \
      for (int t4 = 0; t4 < 4; ++t4) {                                           \
        const unsigned char* pa_ = aBase + (((size_t)(t4 * kTiles + (KT))) << 11); \
        const unsigned char* pb_ = bBase + (((size_t)(t4 * kTiles + (KT))) << 11); \
        GL0(AF[t4].q[0], pa_); GL1(AF[t4].q[1], pa_);                            \
        GL0(BF[t4].q[0], pb_); GL1(BF[t4].q[1], pb_);                            \
      } }

#define MFMAS(AF, BF)                                                            \
    { _Pragma("unroll")                                                          \
      for (int rt = 0; rt < 4; ++rt)                                             \
        _Pragma("unroll")                                                        \
        for (int ct = 0; ct < 4; ++ct)                                           \
          acc[rt][ct] = __builtin_amdgcn_mfma_scale_f32_16x16x128_f8f6f4(        \
              AF[rt].v, BF[ct].v, acc[rt][ct], 0, 0, 0, 127, 0, 127); }

    ISSUE(aX, bX, 0)
    int kt = 0;
    for (;;) {
        if (kt + 1 < kTiles) {
            ISSUE(aY, bY, kt + 1)
            __builtin_amdgcn_sched_barrier(0);
            asm volatile("s_waitcnt vmcnt(16)");   // drain current tile only; next stays in flight
        } else {
            __builtin_amdgcn_sched_barrier(0);
            asm volatile("s_waitcnt vmcnt(0)");
        }
        __builtin_amdgcn_sched_barrier(0);          // rule #18: MFMAs must not hoist above wait
        MFMAS(aX, bX)
        __builtin_amdgcn_sched_barrier(0);
        ++kt; if (kt >= kTiles) break;

        if (kt + 1 < kTiles) {
            ISSUE(aX, bX, kt + 1)
            __builtin_amdgcn_sched_barrier(0);
            asm volatile("s_waitcnt vmcnt(16)");
        } else {
            __builtin_amdgcn_sched_barrier(0);
            asm volatile("s_waitcnt vmcnt(0)");
        }
        __builtin_amdgcn_sched_barrier(0);
        MFMAS(aY, bY)
        __builtin_amdgcn_sched_barrier(0);
        ++kt; if (kt >= kTiles) break;
    }
#undef ISSUE
#undef MFMAS
#undef GL0
#undef GL1

    // ---- epilogue (16x16 C/D: col=lane&15, row=(lane>>4)*4+reg) ----
    const int q  = lane >> 4;
    const int jlo = colBase + wc;
    const int ilo = rowBase + wr;

    int   jn[4];
    float jinv[4];
    bool  jvalid[4];
#pragma unroll
    for (int ct = 0; ct < 4; ++ct) {
        const int j = jlo + ct * 16 + rl;
        jn[ct]  = j;
        jinv[ct] = inv_norm[j];
        jvalid[ct] = (j < M);
    }

    // wave-uniform positive-pair possibility check
    bool posLane = false;
    {
        const int ri = ilo + lane;
        if (ri < M) posLane |= (ends[ri] >= jlo) && (starts[ri] <= jlo + 63);
        if (!isDiag) {
            const int cj = jlo + lane;
            if (cj < M) posLane |= (ends[cj] >= ilo) && (starts[cj] <= ilo + 63);
        }
    }
    const bool fullPath = (__ballot(posLane) != 0ULL);

    float posc[4] = {0.f, 0.f, 0.f, 0.f};
    float negc[4] = {0.f, 0.f, 0.f, 0.f};

    if (fullPath) {
        int   jns[4], jne[4];
        float jsq[4];
#pragma unroll
        for (int ct = 0; ct < 4; ++ct) {
            jsq[ct] = sq[jn[ct]];
            jns[ct] = jvalid[ct] ? starts[jn[ct]] : 0;
            jne[ct] = jvalid[ct] ? ends[jn[ct]]   : -1;
        }
#pragma unroll
        for (int rt = 0; rt < 4; ++rt) {
            const int ibase = ilo + rt * 16 + q * 4;
#pragma unroll
            for (int reg = 0; reg < 4; ++reg) {
                const int i = ibase + reg;
                const bool rowValid = (i < M);
                const int ns = rowValid ? starts[i] : 0;
                const int ne = rowValid ? ends[i]   : -1;
                const float iinv = inv_norm[i];
                const float isq  = sq[i];
                float posp = 0.f, negp = 0.f;
#pragma unroll
                for (int ct = 0; ct < 4; ++ct) {
                    const float dot = acc[rt][ct][reg];
                    const int j = jn[ct];
                    float cosv = dot * iinv * jinv[ct];
                    cosv = fminf(fmaxf(cosv, -1.f), 1.f);
                    float tn = fmaxf(fabsf(cosv) - M_NEG, 0.f);
                    const float nterm = tn * tn;
                    const float d2 = fmaxf(isq + jsq[ct] - 2.f * dot, 0.f);
                    float tp = fmaxf(sqrtf(d2) - M_POS, 0.f);
                    const float pterm = tp * tp;
                    const bool dg = (j == i);
                    if (rowValid) {
                        const bool in_r = (j >= ns) && (j <= ne);
                        if (in_r && !dg) posp += pterm;
                        if (!in_r || dg) negp += nterm;
                    }
                    if (!isDiag && jvalid[ct]) {
                        const bool in_c = (i >= jns[ct]) && (i <= jne[ct]);
                        if (in_c && !dg) posc[ct] += pterm;
                        if (!in_c || dg) negc[ct] += nterm;
                    }
                }
#pragma unroll
                for (int m = 1; m < 16; m <<= 1) {
                    posp += __shfl_xor(posp, m, 64);
                    negp += __shfl_xor(negp, m, 64);
                }
                if (rowValid && rl == 0) {
                    atomicAdd(&pos_acc[i], posp);
                    atomicAdd(&neg_acc[i], negp);
                }
            }
        }
        if (!isDiag) {
#pragma unroll
            for (int ct = 0; ct < 4; ++ct) {
                posc[ct] += __shfl_xor(posc[ct], 16, 64);
                posc[ct] += __shfl_xor(posc[ct], 32, 64);
                negc[ct] += __shfl_xor(negc[ct], 16, 64);
                negc[ct] += __shfl_xor(negc[ct], 32, 64);
            }
            if (q == 0) {
#pragma unroll
                for (int ct = 0; ct < 4; ++ct) {
                    if (jvalid[ct]) {
                        atomicAdd(&pos_acc[jn[ct]], posc[ct]);
                        atomicAdd(&neg_acc[jn[ct]], negc[ct]);
                    }
                }
            }
        }
    } else {
        // fast path: every element is a negative for both its row and its column
#pragma unroll
        for (int rt = 0; rt < 4; ++rt) {
            const int ibase = ilo + rt * 16 + q * 4;
#pragma unroll
            for (int reg = 0; reg < 4; ++reg) {
                const int i = ibase + reg;
                const float iinv = inv_norm[i];
                float negp = 0.f;
#pragma unroll
                for (int ct = 0; ct < 4; ++ct) {
                    const float dot = acc[rt][ct][reg];
                    float cosv = dot * iinv * jinv[ct];
                    cosv = fminf(fmaxf(cosv, -1.f), 1.f);
                    float tn = fmaxf(fabsf(cosv) - M_NEG, 0.f);
                    const float nterm = tn * tn;
                    negp += nterm;
                    negc[ct] += nterm;
                }
#pragma unroll
                for (int m = 1; m < 16; m <<= 1)
                    negp += __shfl_xor(negp, m, 64);
                if ((i < M) && rl == 0)
                    atomicAdd(&neg_acc[i], negp);
            }
        }
        if (!isDiag) {
#pragma unroll
            for (int ct = 0; ct < 4; ++ct) {
                negc[ct] += __shfl_xor(negc[ct], 16, 64);
                negc[ct] += __shfl_xor(negc[ct], 32, 64);
            }
            if (q == 0) {
#pragma unroll
                for (int ct = 0; ct < 4; ++ct)
                    if (jvalid[ct])
                        atomicAdd(&neg_acc[jn[ct]], negc[ct]);
            }
        }
    }

    // ---- last-block finalize (fence/atomic by tid0 only — validated R7) ----
    __shared__ bool amLast;
    __syncthreads();
    if (tid == 0) {
        __threadfence();
        unsigned old = atomicAdd(counter, 1u);
        amLast = (old == (unsigned)(gridDim.x - 1));
    }
    __syncthreads();
    if (amLast) {
        __threadfence();
        float total = 0.f;
        int cnt = 0;
        for (int i = tid; i < M; i += 256) {
            const float pa = __hip_atomic_load(&pos_acc[i], __ATOMIC_RELAXED, __HIP_MEMORY_SCOPE_AGENT);
            const float na = __hip_atomic_load(&neg_acc[i], __ATOMIC_RELAXED, __HIP_MEMORY_SCOPE_AGENT);
            const int ns = starts[i], ne = ends[i];
            const int lo = max(ns, 0), hi = min(ne, N - 1);
            const int inr = max(hi - lo + 1, 0);
            const bool dg = (i >= ns) && (i <= ne);
            const int pos_cnt = inr - (dg ? 1 : 0);
            const int neg_cnt = N - inr + (dg ? 1 : 0);
            if (pos_cnt > 0 && neg_cnt > 0) {
                total += pa / (float)max(pos_cnt, 1)
                       + LAM_NEG * na / (float)max(neg_cnt, 1);
                cnt++;
            }
        }
        for (int o = 32; o > 0; o >>= 1) {
            total += __shfl_down(total, o, 64);
            cnt   += __shfl_down(cnt, o, 64);
        }
        __shared__ float fin_ts[4];
        __shared__ int   fin_cs[4];
        if ((tid & 63) == 0) { fin_ts[tid >> 6] = total; fin_cs[tid >> 6] = cnt; }
        __syncthreads();
        if (tid == 0) {
            float T = fin_ts[0] + fin_ts[1] + fin_ts[2] + fin_ts[3];
            int   C = fin_cs[0] + fin_cs[1] + fin_cs[2] + fin_cs[3];
            out[0] = (C > 0) ? T / (float)C : 0.f;
        }
    }
}

extern "C" void kernel_launch(void* const* d_in, const int* in_sizes, int n_in,
                              void* d_out, int out_size, void* d_ws, size_t ws_size,
                              hipStream_t stream) {
    const float* cb     = (const float*)d_in[0];
    const int*   starts = (const int*)d_in[1];
    const int*   ends   = (const int*)d_in[2];
    const int*   max_ip = (const int*)d_in[3];
    float* out = (float*)d_out;

    const int N = in_sizes[1];
    const int d = in_sizes[0] / N;

    char* ws = (char*)d_ws;
    unsigned char* cb_q = (unsigned char*)ws;
    size_t off = ((size_t)N * d + 255) & ~(size_t)255;
    float* sq       = (float*)(ws + off); off += (size_t)N * 4;
    float* inv_norm = (float*)(ws + off); off += (size_t)N * 4;
    float* pos_acc  = (float*)(ws + off); off += (size_t)N * 4;
    float* neg_acc  = (float*)(ws + off); off += (size_t)N * 4;
    unsigned* counter = (unsigned*)(ws + off); off += 256;

    // prep zeroes pos_acc/neg_acc/counter (2N+1 u32, contiguous)
    prep_kernel<<<(N + 3) / 4, 256, 0, stream>>>(cb, cb_q, sq, inv_norm,
                                                 (unsigned*)pos_acc, 2 * N + 1, N, d);

    const int nb = N / 128;
    const int nBlocks = nb * (nb + 1) / 2;   // upper-triangular tiles
    gram_loss_kernel<<<nBlocks, 256, 0, stream>>>(cb_q, sq, inv_norm, starts, ends,
                                                  max_ip, pos_acc, neg_acc, counter,
                                                  out, N, d);
}